// Round 12
// baseline (187.097 us; speedup 1.0000x reference)
//
#include <hip/hip_runtime.h>
#include <cstdint>
#include <cstddef>

// Problem constants
constexpr int B = 64, S = 2048, H = 512, E = 256, V = 32000;
constexpr int NCHUNK = 32;   // attention: 32 chunks of 64 keys per batch

// ---------------------------------------------------------------------------
// Kernel 1: fused scores + online-softmax partials (enc read exactly once).
// One wave per (b, 64-key chunk); lane covers 8 of 512 dims (2 float4 slices).
// Software-pipelined key loop. Measured ~54 us vs 43 us HBM floor (ledger).
// ---------------------------------------------------------------------------
__global__ __launch_bounds__(256) void attn_part_kernel(
    const float* __restrict__ hd, const float* __restrict__ enc,
    float* __restrict__ m_part, float* __restrict__ l_part,
    float* __restrict__ acc_part)
{
    int b = blockIdx.x >> 3;
    int wave = threadIdx.x >> 6, lane = threadIdx.x & 63;
    int chunk = ((blockIdx.x & 7) << 2) + wave;
    int s0 = chunk * 64;

    const float4* hv = (const float4*)(hd + (size_t)b * H);
    float4 h0 = hv[lane], h1 = hv[64 + lane];
    const float4* ev = (const float4*)(enc + (size_t)b * S * H) + (size_t)s0 * (H / 4);

    float m = -1e30f, l = 0.f;
    float4 a0 = make_float4(0.f, 0.f, 0.f, 0.f);
    float4 a1 = make_float4(0.f, 0.f, 0.f, 0.f);
    float4 e0 = ev[lane], e1 = ev[64 + lane];

    auto process = [&](const float4& pe0, const float4& pe1) {
        float p = pe0.x * h0.x + pe0.y * h0.y + pe0.z * h0.z + pe0.w * h0.w
                + pe1.x * h1.x + pe1.y * h1.y + pe1.z * h1.z + pe1.w * h1.w;
#pragma unroll
        for (int off = 32; off; off >>= 1) p += __shfl_xor(p, off, 64);
        if (p <= m) {                 // wave-uniform branch
            float w = __expf(p - m);
            l += w;
            a0.x += w * pe0.x; a0.y += w * pe0.y; a0.z += w * pe0.z; a0.w += w * pe0.w;
            a1.x += w * pe1.x; a1.y += w * pe1.y; a1.z += w * pe1.z; a1.w += w * pe1.w;
        } else {
            float sc = __expf(m - p); // first iter: exp(-1e30)=0 -> exact init
            m = p;
            l = l * sc + 1.f;
            a0.x = a0.x * sc + pe0.x; a0.y = a0.y * sc + pe0.y;
            a0.z = a0.z * sc + pe0.z; a0.w = a0.w * sc + pe0.w;
            a1.x = a1.x * sc + pe1.x; a1.y = a1.y * sc + pe1.y;
            a1.z = a1.z * sc + pe1.z; a1.w = a1.w * sc + pe1.w;
        }
    };

    for (int s = 0; s < 63; ++s) {
        const float4* r = ev + (size_t)(s + 1) * (H / 4);
        float4 n0 = r[lane], n1 = r[64 + lane];   // prefetch next key
        process(e0, e1);                          // consume current key
        e0 = n0; e1 = n1;
    }
    process(e0, e1);                              // last key

    int base = b * NCHUNK + chunk;
    if (lane == 0) { m_part[base] = m; l_part[base] = l; }
    float4* ap = (float4*)(acc_part + (size_t)base * H);
    ap[lane] = a0; ap[64 + lane] = a1;
}

// ---------------------------------------------------------------------------
// Kernel 2: combine partials -> ctx; embedding gather; transposed LSTM input
// inp_t[k][b]: [0,256)=xe, [256,768)=ctx, [768,1280)=h0.  (~4 us in situ)
// ---------------------------------------------------------------------------
__global__ __launch_bounds__(256) void combine_kernel(
    const float* __restrict__ m_part, const float* __restrict__ l_part,
    const float* __restrict__ acc_part, const int* __restrict__ x,
    const float* __restrict__ emb, const float* __restrict__ h0,
    float* __restrict__ inp_t)
{
    int b = blockIdx.x, t = threadIdx.x;
    float M = -1e30f;
    for (int i = 0; i < NCHUNK; ++i) M = fmaxf(M, m_part[b * NCHUNK + i]);
    float L = 0.f;
    for (int i = 0; i < NCHUNK; ++i)
        L += l_part[b * NCHUNK + i] * __expf(m_part[b * NCHUNK + i] - M);
    float invL = 1.f / L;

    for (int d = t; d < H; d += 256) {
        float s = 0.f;
        for (int i = 0; i < NCHUNK; ++i)
            s += __expf(m_part[b * NCHUNK + i] - M) *
                 acc_part[((size_t)(b * NCHUNK + i)) * H + d];
        inp_t[(E + d) * B + b] = s * invL;
    }
    inp_t[t * B + b] = emb[(size_t)x[b] * E + t];
    for (int d = t; d < H; d += 256)
        inp_t[(E + H + d) * B + b] = h0[b * H + d];
}

// ---------------------------------------------------------------------------
// Kernel 3: fully-fused LSTM layer (round-5 proven version; ~5.5 us/layer).
// ---------------------------------------------------------------------------
__global__ __launch_bounds__(256) void lstm_fused_kernel(
    const float* __restrict__ A1, int lda1, int k1len,
    const float* __restrict__ A2, int lda2, int KT,
    const float* __restrict__ X,
    const float* __restrict__ b_ih, const float* __restrict__ b_hh,
    const float* __restrict__ c_prev,
    float* __restrict__ h_t, float* __restrict__ out_h, float* __restrict__ out_c)
{
    __shared__ float sm[4 * 32 * 20 + 4 * 32 * 64];   // As | Xs  (42.5 KB)
    float (*As)[32][20] = (float(*)[32][20])sm;
    float (*Xs)[32][64] = (float(*)[32][64])(sm + 4 * 32 * 20);
    float (*Ps)[16][64] = (float(*)[16][64])(sm + 4 * 32 * 20); // aliases Xs

    const int t = threadIdx.x;
    const int j0 = blockIdx.x * 4;
    const int QK = KT >> 2;
    const int nIter = QK >> 5;
    const int kq = t >> 6, r = t & 63, ty = r >> 4, tx = r & 15;

    float acc[4][4];
#pragma unroll
    for (int i = 0; i < 4; ++i)
#pragma unroll
        for (int j = 0; j < 4; ++j) acc[i][j] = 0.f;

    for (int it = 0; it < nIter; ++it) {
#pragma unroll
        for (int q = 0; q < 2; ++q) {
            int p = t + q * 256;
            int il = p >> 5, c = p & 31;
            int akq = c >> 3, k4 = (c & 7) * 4;
            int gk = akq * QK + it * 32 + k4;
            int grow = j0 + (il & 3) + 512 * (il >> 2);
            const float* src = (gk < k1len)
                ? A1 + (size_t)grow * lda1 + gk
                : A2 + (size_t)grow * lda2 + (gk - k1len);
            float4 v = *(const float4*)src;
            As[akq][k4 + 0][il] = v.x; As[akq][k4 + 1][il] = v.y;
            As[akq][k4 + 2][il] = v.z; As[akq][k4 + 3][il] = v.w;
        }
#pragma unroll
        for (int q = 0; q < 8; ++q) {
            int p = t + q * 256;
            int kk_all = p >> 4, col = (p & 15) * 4;
            int xkq = kk_all >> 5, kk = kk_all & 31;
            int gk = xkq * QK + it * 32 + kk;
            *(float4*)&Xs[xkq][kk][col] = *(const float4*)&X[(size_t)gk * 64 + col];
        }
        __syncthreads();

#pragma unroll 8
        for (int kk = 0; kk < 32; ++kk) {
            float4 av = *(const float4*)&As[kq][kk][ty * 4];
            float4 xv = *(const float4*)&Xs[kq][kk][tx * 4];
            float aa[4] = {av.x, av.y, av.z, av.w};
            float xx[4] = {xv.x, xv.y, xv.z, xv.w};
#pragma unroll
            for (int i = 0; i < 4; ++i)
#pragma unroll
                for (int j = 0; j < 4; ++j) acc[i][j] += aa[i] * xx[j];
        }
        __syncthreads();
    }

#pragma unroll
    for (int i = 0; i < 4; ++i)
        *(float4*)&Ps[kq][ty * 4 + i][tx * 4] =
            make_float4(acc[i][0], acc[i][1], acc[i][2], acc[i][3]);
    __syncthreads();

    for (int idx = t; idx < 16 * 64; idx += 256) {
        int row = idx >> 6, b = idx & 63;
        Ps[0][row][b] = Ps[0][row][b] + Ps[1][row][b] + Ps[2][row][b] + Ps[3][row][b];
    }
    __syncthreads();

    {
        int jj = t >> 6, b = t & 63;
        int j = j0 + jj;
        float gi = Ps[0][jj][b]      + b_ih[j]        + b_hh[j];
        float gf = Ps[0][4 + jj][b]  + b_ih[j + 512]  + b_hh[j + 512];
        float gg = Ps[0][8 + jj][b]  + b_ih[j + 1024] + b_hh[j + 1024];
        float go = Ps[0][12 + jj][b] + b_ih[j + 1536] + b_hh[j + 1536];
        float iv = 1.f / (1.f + __expf(-gi));
        float fv = 1.f / (1.f + __expf(-gf));
        float gv = tanhf(gg);
        float ov = 1.f / (1.f + __expf(-go));
        float cp = c_prev ? c_prev[b * H + j] : 0.f;
        float c2 = fv * cp + iv * gv;
        float hv = ov * tanhf(c2);
        h_t[j * B + b] = hv;
        if (out_h) { out_h[b * H + j] = hv; out_c[b * H + j] = c2; }
    }
}

// ---------------------------------------------------------------------------
// Kernel 4 (v8): fc logits = z^T @ fc_w^T + fc_b.
// v7 retro: LDS-INSTRUCTION-throughput-bound (2 ds_read_b128 per 16 FMA ->
// 96k LDS cyc/CU vs 32k VALU cyc/CU = 3:1). v8: micro 4x8 -> 3 reads per
// 32 FMA (2.25:1, predicted ~30-38 us). BM=64, 128 thr (2 waves), grid 500
// -> ~4 blocks/CU = 8 waves/CU; LDS 16.7 KB; VGPR ~80 (acc 32 + frags 12),
// no spill. Same proven staging (A transposed [32][68], pad 4).
// ---------------------------------------------------------------------------
__global__ __launch_bounds__(128) void fc_gemm_kernel(
    const float* __restrict__ A, const float* __restrict__ X,
    float* __restrict__ outp, const float* __restrict__ bias)
{
    __shared__ float As[32][68];    // [k][row], +4 pad  (8.7 KB)
    __shared__ float Xs[32][64];    // (8 KB)

    const int t = threadIdx.x;      // 0..127
    const int tx = t & 7;           // col group: cols 8*tx .. +7
    const int ty = t >> 3;          // row group: rows m0 + 4*ty .. +3 (ty<16)
    const int m0 = blockIdx.x * 64;

    float acc[4][8];
#pragma unroll
    for (int i = 0; i < 4; ++i)
#pragma unroll
        for (int j = 0; j < 8; ++j) acc[i][j] = 0.f;

    for (int k0 = 0; k0 < 512; k0 += 32) {
        // stage A tile: 64 rows x 32 k, transposed. 4 float4/thread.
        // 8 lanes cover one row's 128 B contiguous -> coalesced.
#pragma unroll
        for (int q = 0; q < 4; ++q) {
            int row = (t >> 3) + q * 16;
            int k4 = (t & 7) * 4;
            float4 v = *(const float4*)&A[(size_t)(m0 + row) * 512 + k0 + k4];
            As[k4 + 0][row] = v.x; As[k4 + 1][row] = v.y;
            As[k4 + 2][row] = v.z; As[k4 + 3][row] = v.w;
        }
        // stage X tile: 32 k x 64 cols. 4 float4/thread.
#pragma unroll
        for (int q = 0; q < 4; ++q) {
            int p = t + q * 128;
            int row = p >> 4, col = (p & 15) * 4;
            *(float4*)&Xs[row][col] =
                *(const float4*)&X[(size_t)(k0 + row) * 64 + col];
        }
        __syncthreads();

#pragma unroll 8
        for (int k = 0; k < 32; ++k) {
            float4 av  = *(const float4*)&As[k][ty * 4];
            float4 xv0 = *(const float4*)&Xs[k][tx * 8];
            float4 xv1 = *(const float4*)&Xs[k][tx * 8 + 4];
            float aa[4] = {av.x, av.y, av.z, av.w};
            float xx[8] = {xv0.x, xv0.y, xv0.z, xv0.w,
                           xv1.x, xv1.y, xv1.z, xv1.w};
#pragma unroll
            for (int i = 0; i < 4; ++i)
#pragma unroll
                for (int j = 0; j < 8; ++j)
                    acc[i][j] += aa[i] * xx[j];
        }
        __syncthreads();
    }

    // epilogue: out[b][v], b = 8*tx+j, v = m0+4*ty .. +3 (float4 writes)
#pragma unroll
    for (int j = 0; j < 8; ++j) {
        int b = tx * 8 + j;
        int v0 = m0 + ty * 4;
        float4 w;
        w.x = acc[0][j] + bias[v0 + 0];
        w.y = acc[1][j] + bias[v0 + 1];
        w.z = acc[2][j] + bias[v0 + 2];
        w.w = acc[3][j] + bias[v0 + 3];
        *(float4*)&outp[(size_t)b * V + v0] = w;
    }
}

// ---------------------------------------------------------------------------
extern "C" void kernel_launch(void* const* d_in, const int* in_sizes, int n_in,
                              void* d_out, int out_size, void* d_ws, size_t ws_size,
                              hipStream_t stream)
{
    const int*   x     = (const int*)d_in[0];
    const float* hdec  = (const float*)d_in[1];
    const float* enc   = (const float*)d_in[2];
    const float* h0    = (const float*)d_in[3];
    const float* c0    = (const float*)d_in[4];
    const float* emb   = (const float*)d_in[5];
    const float* w_ih1 = (const float*)d_in[6];
    const float* w_hh1 = (const float*)d_in[7];
    const float* b_ih1 = (const float*)d_in[8];
    const float* b_hh1 = (const float*)d_in[9];
    const float* w_ih  = (const float*)d_in[10];
    // d_in[11] = w_hh: multiplied by zero hidden state in layers 2-4 -> skipped
    const float* b_ih  = (const float*)d_in[12];
    const float* b_hh  = (const float*)d_in[13];
    const float* fc_w  = (const float*)d_in[14];
    const float* fc_b  = (const float*)d_in[15];

    float* out = (float*)d_out;
    float* ws  = (float*)d_ws;

    float* m_part   = ws;                                // 2048
    float* l_part   = ws + 2048;                         // 2048
    float* acc_part = ws + 4096;                         // 64*32*512
    float* inp_t    = acc_part + (size_t)B * NCHUNK * H; // 1280*64
    float* zA       = inp_t + 1280 * B;                  // 512*64
    float* zB       = zA + H * B;                        // 512*64

    float* out_h = out + (size_t)B * V;
    float* out_c = out_h + (size_t)B * H;

    // 1) attention (enc read once, 268 MB)
    attn_part_kernel<<<512, 256, 0, stream>>>(hdec, enc, m_part, l_part, acc_part);
    combine_kernel<<<64, 256, 0, stream>>>(m_part, l_part, acc_part, x, emb, h0, inp_t);

    // 2) LSTM layer 1: K = 768 (w_ih1) | 512 (w_hh1) = 1280, real c0
    lstm_fused_kernel<<<128, 256, 0, stream>>>(
        w_ih1, 768, 768, w_hh1, 512, 1280, inp_t,
        b_ih1, b_hh1, c0, zA, nullptr, nullptr);

    // 3) LSTM layers 2-4 (zero h/c: only w_ih contributes), K = 512
    lstm_fused_kernel<<<128, 256, 0, stream>>>(
        w_ih + 0 * (size_t)2048 * H, 512, 512, nullptr, 0, 512, zA,
        b_ih + 0 * 2048, b_hh + 0 * 2048, nullptr, zB, nullptr, nullptr);
    lstm_fused_kernel<<<128, 256, 0, stream>>>(
        w_ih + 1 * (size_t)2048 * H, 512, 512, nullptr, 0, 512, zB,
        b_ih + 1 * 2048, b_hh + 1 * 2048, nullptr, zA, nullptr, nullptr);
    lstm_fused_kernel<<<128, 256, 0, stream>>>(
        w_ih + 2 * (size_t)2048 * H, 512, 512, nullptr, 0, 512, zA,
        b_ih + 2 * 2048, b_hh + 2 * 2048, nullptr, zB, out_h, out_c);

    // 4) logits = zB^T @ fc_w^T + fc_b  (micro 4x8, 128 thr, 500 blocks)
    fc_gemm_kernel<<<500, 128, 0, stream>>>(fc_w, zB, out, fc_b);
}

// Round 13
// 151.971 us; speedup vs baseline: 1.2311x; 1.2311x over previous
//
#include <hip/hip_runtime.h>
#include <cstdint>
#include <cstddef>

// Problem constants
constexpr int B = 64, S = 2048, H = 512, E = 256, V = 32000;
constexpr int NCHUNK = 32;   // attention: 32 chunks of 64 keys per batch

using bf16x8 = __attribute__((ext_vector_type(8))) short;
using f32x4  = __attribute__((ext_vector_type(4))) float;

static __device__ __forceinline__ unsigned short f2bf(float f) {
    unsigned u = __float_as_uint(f);
    u = u + 0x7fffu + ((u >> 16) & 1u);    // RNE
    return (unsigned short)(u >> 16);
}
static __device__ __forceinline__ float bf2f(unsigned short h) {
    return __uint_as_float(((unsigned)h) << 16);
}

// ---------------------------------------------------------------------------
// Kernel 1: fused scores + online-softmax partials (enc read exactly once).
// One wave per (b, 64-key chunk); software-pipelined key loop. ~54 us.
// ---------------------------------------------------------------------------
__global__ __launch_bounds__(256) void attn_part_kernel(
    const float* __restrict__ hd, const float* __restrict__ enc,
    float* __restrict__ m_part, float* __restrict__ l_part,
    float* __restrict__ acc_part)
{
    int b = blockIdx.x >> 3;
    int wave = threadIdx.x >> 6, lane = threadIdx.x & 63;
    int chunk = ((blockIdx.x & 7) << 2) + wave;
    int s0 = chunk * 64;

    const float4* hv = (const float4*)(hd + (size_t)b * H);
    float4 h0 = hv[lane], h1 = hv[64 + lane];
    const float4* ev = (const float4*)(enc + (size_t)b * S * H) + (size_t)s0 * (H / 4);

    float m = -1e30f, l = 0.f;
    float4 a0 = make_float4(0.f, 0.f, 0.f, 0.f);
    float4 a1 = make_float4(0.f, 0.f, 0.f, 0.f);
    float4 e0 = ev[lane], e1 = ev[64 + lane];

    auto process = [&](const float4& pe0, const float4& pe1) {
        float p = pe0.x * h0.x + pe0.y * h0.y + pe0.z * h0.z + pe0.w * h0.w
                + pe1.x * h1.x + pe1.y * h1.y + pe1.z * h1.z + pe1.w * h1.w;
#pragma unroll
        for (int off = 32; off; off >>= 1) p += __shfl_xor(p, off, 64);
        if (p <= m) {                 // wave-uniform branch
            float w = __expf(p - m);
            l += w;
            a0.x += w * pe0.x; a0.y += w * pe0.y; a0.z += w * pe0.z; a0.w += w * pe0.w;
            a1.x += w * pe1.x; a1.y += w * pe1.y; a1.z += w * pe1.z; a1.w += w * pe1.w;
        } else {
            float sc = __expf(m - p); // first iter: exp(-1e30)=0 -> exact init
            m = p;
            l = l * sc + 1.f;
            a0.x = a0.x * sc + pe0.x; a0.y = a0.y * sc + pe0.y;
            a0.z = a0.z * sc + pe0.z; a0.w = a0.w * sc + pe0.w;
            a1.x = a1.x * sc + pe1.x; a1.y = a1.y * sc + pe1.y;
            a1.z = a1.z * sc + pe1.z; a1.w = a1.w * sc + pe1.w;
        }
    };

    for (int s = 0; s < 63; ++s) {
        const float4* r = ev + (size_t)(s + 1) * (H / 4);
        float4 n0 = r[lane], n1 = r[64 + lane];   // prefetch next key
        process(e0, e1);                          // consume current key
        e0 = n0; e1 = n1;
    }
    process(e0, e1);                              // last key

    int base = b * NCHUNK + chunk;
    if (lane == 0) { m_part[base] = m; l_part[base] = l; }
    float4* ap = (float4*)(acc_part + (size_t)base * H);
    ap[lane] = a0; ap[64 + lane] = a1;
}

// ---------------------------------------------------------------------------
// Kernel 2: combine partials -> ctx; embedding gather; transposed LSTM input
// inp_t[k][b]: [0,256)=xe, [256,768)=ctx, [768,1280)=h0.  (~4 us in situ)
// ---------------------------------------------------------------------------
__global__ __launch_bounds__(256) void combine_kernel(
    const float* __restrict__ m_part, const float* __restrict__ l_part,
    const float* __restrict__ acc_part, const int* __restrict__ x,
    const float* __restrict__ emb, const float* __restrict__ h0,
    float* __restrict__ inp_t)
{
    int b = blockIdx.x, t = threadIdx.x;
    float M = -1e30f;
    for (int i = 0; i < NCHUNK; ++i) M = fmaxf(M, m_part[b * NCHUNK + i]);
    float L = 0.f;
    for (int i = 0; i < NCHUNK; ++i)
        L += l_part[b * NCHUNK + i] * __expf(m_part[b * NCHUNK + i] - M);
    float invL = 1.f / L;

    for (int d = t; d < H; d += 256) {
        float s = 0.f;
        for (int i = 0; i < NCHUNK; ++i)
            s += __expf(m_part[b * NCHUNK + i] - M) *
                 acc_part[((size_t)(b * NCHUNK + i)) * H + d];
        inp_t[(E + d) * B + b] = s * invL;
    }
    inp_t[t * B + b] = emb[(size_t)x[b] * E + t];
    for (int d = t; d < H; d += 256)
        inp_t[(E + H + d) * B + b] = h0[b * H + d];
}

// ---------------------------------------------------------------------------
// Kernel 3: fully-fused LSTM layer (round-5 proven version; ~5.5 us/layer).
// ---------------------------------------------------------------------------
__global__ __launch_bounds__(256) void lstm_fused_kernel(
    const float* __restrict__ A1, int lda1, int k1len,
    const float* __restrict__ A2, int lda2, int KT,
    const float* __restrict__ X,
    const float* __restrict__ b_ih, const float* __restrict__ b_hh,
    const float* __restrict__ c_prev,
    float* __restrict__ h_t, float* __restrict__ out_h, float* __restrict__ out_c)
{
    __shared__ float sm[4 * 32 * 20 + 4 * 32 * 64];   // As | Xs  (42.5 KB)
    float (*As)[32][20] = (float(*)[32][20])sm;
    float (*Xs)[32][64] = (float(*)[32][64])(sm + 4 * 32 * 20);
    float (*Ps)[16][64] = (float(*)[16][64])(sm + 4 * 32 * 20); // aliases Xs

    const int t = threadIdx.x;
    const int j0 = blockIdx.x * 4;
    const int QK = KT >> 2;
    const int nIter = QK >> 5;
    const int kq = t >> 6, r = t & 63, ty = r >> 4, tx = r & 15;

    float acc[4][4];
#pragma unroll
    for (int i = 0; i < 4; ++i)
#pragma unroll
        for (int j = 0; j < 4; ++j) acc[i][j] = 0.f;

    for (int it = 0; it < nIter; ++it) {
#pragma unroll
        for (int q = 0; q < 2; ++q) {
            int p = t + q * 256;
            int il = p >> 5, c = p & 31;
            int akq = c >> 3, k4 = (c & 7) * 4;
            int gk = akq * QK + it * 32 + k4;
            int grow = j0 + (il & 3) + 512 * (il >> 2);
            const float* src = (gk < k1len)
                ? A1 + (size_t)grow * lda1 + gk
                : A2 + (size_t)grow * lda2 + (gk - k1len);
            float4 v = *(const float4*)src;
            As[akq][k4 + 0][il] = v.x; As[akq][k4 + 1][il] = v.y;
            As[akq][k4 + 2][il] = v.z; As[akq][k4 + 3][il] = v.w;
        }
#pragma unroll
        for (int q = 0; q < 8; ++q) {
            int p = t + q * 256;
            int kk_all = p >> 4, col = (p & 15) * 4;
            int xkq = kk_all >> 5, kk = kk_all & 31;
            int gk = xkq * QK + it * 32 + kk;
            *(float4*)&Xs[xkq][kk][col] = *(const float4*)&X[(size_t)gk * 64 + col];
        }
        __syncthreads();

#pragma unroll 8
        for (int kk = 0; kk < 32; ++kk) {
            float4 av = *(const float4*)&As[kq][kk][ty * 4];
            float4 xv = *(const float4*)&Xs[kq][kk][tx * 4];
            float aa[4] = {av.x, av.y, av.z, av.w};
            float xx[4] = {xv.x, xv.y, xv.z, xv.w};
#pragma unroll
            for (int i = 0; i < 4; ++i)
#pragma unroll
                for (int j = 0; j < 4; ++j) acc[i][j] += aa[i] * xx[j];
        }
        __syncthreads();
    }

#pragma unroll
    for (int i = 0; i < 4; ++i)
        *(float4*)&Ps[kq][ty * 4 + i][tx * 4] =
            make_float4(acc[i][0], acc[i][1], acc[i][2], acc[i][3]);
    __syncthreads();

    for (int idx = t; idx < 16 * 64; idx += 256) {
        int row = idx >> 6, b = idx & 63;
        Ps[0][row][b] = Ps[0][row][b] + Ps[1][row][b] + Ps[2][row][b] + Ps[3][row][b];
    }
    __syncthreads();

    {
        int jj = t >> 6, b = t & 63;
        int j = j0 + jj;
        float gi = Ps[0][jj][b]      + b_ih[j]        + b_hh[j];
        float gf = Ps[0][4 + jj][b]  + b_ih[j + 512]  + b_hh[j + 512];
        float gg = Ps[0][8 + jj][b]  + b_ih[j + 1024] + b_hh[j + 1024];
        float go = Ps[0][12 + jj][b] + b_ih[j + 1536] + b_hh[j + 1536];
        float iv = 1.f / (1.f + __expf(-gi));
        float fv = 1.f / (1.f + __expf(-gf));
        float gv = tanhf(gg);
        float ov = 1.f / (1.f + __expf(-go));
        float cp = c_prev ? c_prev[b * H + j] : 0.f;
        float c2 = fv * cp + iv * gv;
        float hv = ov * tanhf(c2);
        h_t[j * B + b] = hv;
        if (out_h) { out_h[b * H + j] = hv; out_c[b * H + j] = c2; }
    }
}

// ---------------------------------------------------------------------------
// Kernel 4 (v9): fc logits via bf16 MFMA (16x16x32), fp32 accumulate.
// fp32-vector fc is capped ~53 us by LDS-instruction throughput (v6-v8).
// MFMA cuts LDS to 4 b128 per 8 MFMA -> HBM-bound (~10.4 us floor on 64 MB).
// Accuracy: W split whi+wlo (2 bf16 -> 2 MFMA, W rounding cancels); residual
// = z bf16 rounding only, est absmax ~1-2e-5 < 5.77e-5 threshold.
// Layout (m89/m92-verified convention):
//   A frag: lane l holds W[m0+(l&15)][k0+(l>>4)*8 .. +7]  (k-contiguous x8)
//   B frag: lane l holds z[b=bt*16+(l&15)][k0+(l>>4)*8 .. +7] (B^T rows)
//   D: col(batch)=l&15, row(vocab)=(l>>4)*4+reg
// z staged once/block as bf16 [64][512], XOR-swizzled (byte ^= (b&7)<<4).
// 500 blocks x 256 thr (4 waves x 16 vocab rows), 8 waves/CU.
// ---------------------------------------------------------------------------
__global__ __launch_bounds__(256) void fc_mfma_kernel(
    const float* __restrict__ A, const float* __restrict__ X,
    float* __restrict__ outp, const float* __restrict__ bias)
{
    __shared__ unsigned short zb[64 * 512];   // 64 KB, [b][k] bf16 swizzled

    const int t = threadIdx.x;

    // ---- stage z -> bf16 [b][k], swizzled. thread: b = t&63, 32 k-quads.
    {
        int b = t & 63;
        int kq0 = (t >> 6) * 4;
        for (int q = 0; q < 32; ++q) {
            int k = kq0 + q * 16;
            float f0 = X[(size_t)(k + 0) * 64 + b];
            float f1 = X[(size_t)(k + 1) * 64 + b];
            float f2 = X[(size_t)(k + 2) * 64 + b];
            float f3 = X[(size_t)(k + 3) * 64 + b];
            unsigned lo = (unsigned)f2bf(f0) | ((unsigned)f2bf(f1) << 16);
            unsigned hi = (unsigned)f2bf(f2) | ((unsigned)f2bf(f3) << 16);
            int byte = (b << 10) + (k << 1);
            byte ^= (b & 7) << 4;
            *(uint2*)((char*)zb + byte) = make_uint2(lo, hi);
        }
    }
    __syncthreads();

    const int wv = t >> 6;            // wave id: 16-row vocab group
    const int l  = t & 63;
    const int row = l & 15, kq = l >> 4;
    const int m0 = blockIdx.x * 64 + wv * 16;
    const float* Arow = A + (size_t)(m0 + row) * 512 + kq * 8;

    f32x4 acc[4];
#pragma unroll
    for (int bt = 0; bt < 4; ++bt) acc[bt] = (f32x4){0.f, 0.f, 0.f, 0.f};

    for (int k0 = 0; k0 < 512; k0 += 32) {
        float4 wa = *(const float4*)(Arow + k0);
        float4 wb = *(const float4*)(Arow + k0 + 4);
        float wf[8] = {wa.x, wa.y, wa.z, wa.w, wb.x, wb.y, wb.z, wb.w};
        bf16x8 whi, wlo;
#pragma unroll
        for (int j = 0; j < 8; ++j) {
            unsigned short h = f2bf(wf[j]);
            whi[j] = (short)h;
            wlo[j] = (short)f2bf(wf[j] - bf2f(h));
        }
#pragma unroll
        for (int bt = 0; bt < 4; ++bt) {
            int b = bt * 16 + row;
            int byte = (b << 10) + ((k0 + kq * 8) << 1);
            byte ^= (b & 7) << 4;
            bf16x8 zf = *(const bf16x8*)((const char*)zb + byte);
            acc[bt] = __builtin_amdgcn_mfma_f32_16x16x32_bf16(whi, zf, acc[bt], 0, 0, 0);
            acc[bt] = __builtin_amdgcn_mfma_f32_16x16x32_bf16(wlo, zf, acc[bt], 0, 0, 0);
        }
    }

    // epilogue: D row(vocab) = kq*4 + reg, col(batch) = row(=l&15)
    int v0 = m0 + kq * 4;
    float4 bv = *(const float4*)&bias[v0];
#pragma unroll
    for (int bt = 0; bt < 4; ++bt) {
        int b = bt * 16 + row;
        float4 o;
        o.x = acc[bt][0] + bv.x;
        o.y = acc[bt][1] + bv.y;
        o.z = acc[bt][2] + bv.z;
        o.w = acc[bt][3] + bv.w;
        *(float4*)&outp[(size_t)b * V + v0] = o;
    }
}

// ---------------------------------------------------------------------------
extern "C" void kernel_launch(void* const* d_in, const int* in_sizes, int n_in,
                              void* d_out, int out_size, void* d_ws, size_t ws_size,
                              hipStream_t stream)
{
    const int*   x     = (const int*)d_in[0];
    const float* hdec  = (const float*)d_in[1];
    const float* enc   = (const float*)d_in[2];
    const float* h0    = (const float*)d_in[3];
    const float* c0    = (const float*)d_in[4];
    const float* emb   = (const float*)d_in[5];
    const float* w_ih1 = (const float*)d_in[6];
    const float* w_hh1 = (const float*)d_in[7];
    const float* b_ih1 = (const float*)d_in[8];
    const float* b_hh1 = (const float*)d_in[9];
    const float* w_ih  = (const float*)d_in[10];
    // d_in[11] = w_hh: multiplied by zero hidden state in layers 2-4 -> skipped
    const float* b_ih  = (const float*)d_in[12];
    const float* b_hh  = (const float*)d_in[13];
    const float* fc_w  = (const float*)d_in[14];
    const float* fc_b  = (const float*)d_in[15];

    float* out = (float*)d_out;
    float* ws  = (float*)d_ws;

    float* m_part   = ws;                                // 2048
    float* l_part   = ws + 2048;                         // 2048
    float* acc_part = ws + 4096;                         // 64*32*512
    float* inp_t    = acc_part + (size_t)B * NCHUNK * H; // 1280*64
    float* zA       = inp_t + 1280 * B;                  // 512*64
    float* zB       = zA + H * B;                        // 512*64

    float* out_h = out + (size_t)B * V;
    float* out_c = out_h + (size_t)B * H;

    // 1) attention (enc read once, 268 MB)
    attn_part_kernel<<<512, 256, 0, stream>>>(hdec, enc, m_part, l_part, acc_part);
    combine_kernel<<<64, 256, 0, stream>>>(m_part, l_part, acc_part, x, emb, h0, inp_t);

    // 2) LSTM layer 1: K = 768 (w_ih1) | 512 (w_hh1) = 1280, real c0
    lstm_fused_kernel<<<128, 256, 0, stream>>>(
        w_ih1, 768, 768, w_hh1, 512, 1280, inp_t,
        b_ih1, b_hh1, c0, zA, nullptr, nullptr);

    // 3) LSTM layers 2-4 (zero h/c: only w_ih contributes), K = 512
    lstm_fused_kernel<<<128, 256, 0, stream>>>(
        w_ih + 0 * (size_t)2048 * H, 512, 512, nullptr, 0, 512, zA,
        b_ih + 0 * 2048, b_hh + 0 * 2048, nullptr, zB, nullptr, nullptr);
    lstm_fused_kernel<<<128, 256, 0, stream>>>(
        w_ih + 1 * (size_t)2048 * H, 512, 512, nullptr, 0, 512, zB,
        b_ih + 1 * 2048, b_hh + 1 * 2048, nullptr, zA, nullptr, nullptr);
    lstm_fused_kernel<<<128, 256, 0, stream>>>(
        w_ih + 2 * (size_t)2048 * H, 512, 512, nullptr, 0, 512, zA,
        b_ih + 2 * 2048, b_hh + 2 * 2048, nullptr, zB, out_h, out_c);

    // 4) logits = zB^T @ fc_w^T + fc_b  (bf16 MFMA, split-W compensation)
    fc_mfma_kernel<<<500, 256, 0, stream>>>(fc_w, zB, out, fc_b);
}